// Round 3
// baseline (207.626 us; speedup 1.0000x reference)
//
#include <hip/hip_runtime.h>
#include <math.h>

// Problem constants (from reference): B=4, T=8192, D=512, S=16
#define B_ 4
#define T_ 8192
#define D_ 512
#define S_ 16

// tokens per block for attn_ts_k (32 -> 1024 blocks = 4 blocks/CU).
#define CHUNK 32

// centers LDS row stride in floats: 512+4 keeps 16B alignment for b128
// reads and caps bank conflicts at 2-way (free per CDNA4 measurement).
#define CPAD 516

// ---------------------------------------------------------------------------
// OCCUPANCY LAW (measured R0/R1/R2 on this kernel family, gfx950):
//   VGPR <= 64        -> 4 waves/SIMD   (R1: occ 39.6%)
//   64 < VGPR <= 128  -> 2 waves/SIMD   (R0/R2: occ ~17% even with big grid)
// __launch_bounds__(256,4) makes hipcc cap allocation at 64 VGPRs. That is
// FATAL if true register need exceeds the cap (R1: c_reg[16][2]=128 regs
// spilled, 2.2x regression) but safe+beneficial when true need < 64.
// This version is designed to need ~55 VGPRs: centers moved to LDS,
// lane = (token, splat) so per-lane state is just {x*c, x^2} accumulators.
// ---------------------------------------------------------------------------

__device__ __forceinline__ float dot4(float4 a, float4 b) {
  return a.x * b.x + a.y * b.y + a.z * b.z + a.w * b.w;
}

// ---------------------------------------------------------------------------
// Fused attn + token->splat aggregation. Block = 256 threads (4 waves);
// 1024 blocks = B * T/32 chunks.
//
// Phase A (lane-per-(token,splat)): wave handles 4 tokens per pass, 2
// passes. Lane (tl,s) streams x[token] from global (16 lanes share each
// address -> one cacheline) against LDS-resident centers[s], accumulating
// x.c and x^2. Softmax over s = 4 xor-shuffles within 16-lane groups.
// attn store is lane-contiguous (offset == lane).
//
// Phase B: unchanged from R0/R2 (proven): thread owns cols d, d+256;
// re-streams chunk's x rows (L2-hot) against LDS-broadcast attn; 32
// atomicAdds into L2-resident ts.
// ---------------------------------------------------------------------------
__global__ __launch_bounds__(256, 4) void attn_ts_k(const float* __restrict__ x,
                                                    const float* __restrict__ centers,
                                                    const float* __restrict__ log_scales,
                                                    float* __restrict__ attn,
                                                    float* __restrict__ ts) {
  __shared__ __align__(16) float c_s[S_ * CPAD];  // 33 KB
  __shared__ __align__(16) float a_s[CHUNK][S_];  // 2 KB
  const int tid = threadIdx.x;
  const int lane = tid & 63;
  const int w = tid >> 6;        // wave 0..3
  const int s = lane & 15;       // this lane's splat
  const int tl = lane >> 4;      // this lane's token-in-group 0..3
  const int b = blockIdx.x >> 8;             // 256 chunks per batch
  const int t0 = (blockIdx.x & 255) * CHUNK; // 32 tokens per block

  // ---- stage centers [16][512] -> LDS (padded stride) ----
#pragma unroll
  for (int j = 0; j < 8; ++j) {
    int idx = j * 256 + tid;   // float4 index 0..2047
    int row = idx >> 7;        // 0..15  (128 float4 per row)
    int col = idx & 127;
    float4 v = ((const float4*)centers)[idx];
    *(float4*)(&c_s[row * CPAD + (col << 2)]) = v;
  }
  __syncthreads();

  // ---- per-lane c2 for splat s (redundant across tl/waves, tiny) ----
  float c2 = 0.f;
#pragma unroll 4
  for (int d = 0; d < D_; d += 4) {
    float4 cv = *(const float4*)(&c_s[s * CPAD + d]);
    c2 += dot4(cv, cv);
  }

  const float sc = fminf(fmaxf(__expf(log_scales[s]), 0.1f), 2.0f);
  const float inv2 = 0.5f / (sc * sc);

  // ---- Phase A: 2 passes x 4 tokens per wave ----
#pragma unroll 1
  for (int pass = 0; pass < 2; ++pass) {
    const int wtok = (w << 3) + (pass << 2) + tl;  // block-local token 0..31
    const float* xrow = x + ((size_t)b * T_ + t0 + wtok) * D_;

    float xc = 0.f, x2 = 0.f;
#pragma unroll 1
    for (int d = 0; d < D_; d += 16) {
      float4 xa = *(const float4*)(xrow + d);
      float4 xb = *(const float4*)(xrow + d + 4);
      float4 xv = *(const float4*)(xrow + d + 8);
      float4 xd = *(const float4*)(xrow + d + 12);
      float4 ca = *(const float4*)(&c_s[s * CPAD + d]);
      float4 cb = *(const float4*)(&c_s[s * CPAD + d + 4]);
      float4 cc = *(const float4*)(&c_s[s * CPAD + d + 8]);
      float4 cd = *(const float4*)(&c_s[s * CPAD + d + 12]);
      xc += dot4(xa, ca) + dot4(xb, cb) + dot4(xv, cc) + dot4(xd, cd);
      x2 += dot4(xa, xa) + dot4(xb, xb) + dot4(xv, xv) + dot4(xd, xd);
    }

    float logit = -(x2 + c2 - 2.f * xc) * inv2;

    // softmax across the 16 splat lanes of this token
    float m = logit;
    m = fmaxf(m, __shfl_xor(m, 1, 64));
    m = fmaxf(m, __shfl_xor(m, 2, 64));
    m = fmaxf(m, __shfl_xor(m, 4, 64));
    m = fmaxf(m, __shfl_xor(m, 8, 64));
    float e = __expf(logit - m);
    float sum = e;
    sum += __shfl_xor(sum, 1, 64);
    sum += __shfl_xor(sum, 2, 64);
    sum += __shfl_xor(sum, 4, 64);
    sum += __shfl_xor(sum, 8, 64);
    float a = e / sum;

    attn[((size_t)b * T_ + t0 + wtok) * S_ + s] = a;  // contiguous: off==lane
    a_s[wtok][s] = a;
  }

  __syncthreads();

  // ---- Phase B (unchanged, proven) ----
  {
    const int d = tid;  // owns cols d and d+256
    float2 acc[S_];
#pragma unroll
    for (int si = 0; si < S_; ++si) acc[si] = make_float2(0.f, 0.f);

    const float* xb = x + ((size_t)b * T_ + t0) * D_;

#pragma unroll 4
    for (int t = 0; t < CHUNK; ++t) {
      float xv0 = xb[(size_t)t * D_ + d];
      float xv1 = xb[(size_t)t * D_ + d + 256];
      const float4* ap = (const float4*)a_s[t];  // LDS broadcast
      float4 q0 = ap[0], q1 = ap[1], q2 = ap[2], q3 = ap[3];
      float av[S_] = {q0.x, q0.y, q0.z, q0.w, q1.x, q1.y, q1.z, q1.w,
                      q2.x, q2.y, q2.z, q2.w, q3.x, q3.y, q3.z, q3.w};
#pragma unroll
      for (int si = 0; si < S_; ++si) {
        acc[si].x += av[si] * xv0;
        acc[si].y += av[si] * xv1;
      }
    }

    float* tb = ts + (size_t)b * S_ * D_;
#pragma unroll
    for (int si = 0; si < S_; ++si) {
      atomicAdd(tb + si * D_ + d, acc[si].x);
      atomicAdd(tb + si * D_ + d + 256, acc[si].y);
    }
  }
}

// ---------------------------------------------------------------------------
// Kernel 2 (x2): out[r,e] = sum_k in[r,k] * W[e,k]   (r = 0..63 = b*S+s)
// Split-K=4 reduced in LDS (deterministic). 512 blocks x 256 threads.
// ---------------------------------------------------------------------------
__global__ __launch_bounds__(256) void proj_k(const float* __restrict__ in,
                                              const float* __restrict__ W,
                                              float* __restrict__ out) {
  __shared__ float red[4][64];
  const int r = blockIdx.x >> 3;
  const int eb = blockIdx.x & 7;
  const int el = threadIdx.x & 63;
  const int kc = threadIdx.x >> 6;
  const int e = (eb << 6) + el;

  const float4* w4 = (const float4*)(W + (size_t)e * D_ + kc * 128);
  const float4* i4 = (const float4*)(in + (size_t)r * D_ + kc * 128);
  float acc = 0.f;
#pragma unroll
  for (int k = 0; k < 32; ++k) acc += dot4(w4[k], i4[k]);

  red[kc][el] = acc;
  __syncthreads();
  if (kc == 0)
    out[(size_t)r * D_ + e] = red[0][el] + red[1][el] + red[2][el] + red[3][el];
}

// ---------------------------------------------------------------------------
// Kernel 3: out[b,t,e] = sum_s attn[b,t,s] * ss_o[b,s,e]
// EXACT R0 form (512 blocks, 64 tokens, float2 ssf): float2[16] keeps VGPR
// under 64 -> 4 waves/SIMD. (R2's float4 ssf pushed VGPR past 64 -> halved
// occupancy, ~25 us regression. R1's (256,4)+float4 spilled: 193 us.)
// ---------------------------------------------------------------------------
#define K4_TOK 64
__global__ __launch_bounds__(256) void out_k(const float* __restrict__ attn,
                                             const float* __restrict__ ss_o,
                                             float* __restrict__ out) {
  const int chunks = T_ / K4_TOK;  // 128
  const int b = blockIdx.x / chunks;
  const int t0 = (blockIdx.x % chunks) * K4_TOK;
  const int w = threadIdx.x >> 6;
  const int lane = threadIdx.x & 63;
  const int e0 = (w << 7) + (lane << 1);

  float2 ssf[S_];
  const float* sb = ss_o + (size_t)b * S_ * D_;
#pragma unroll
  for (int s = 0; s < S_; ++s) ssf[s] = *(const float2*)(sb + s * D_ + e0);

  const float4* ab = (const float4*)(attn + ((size_t)b * T_ + t0) * S_);
  float* ob = out + ((size_t)b * T_ + t0) * D_ + e0;

#pragma unroll 4
  for (int t = 0; t < K4_TOK; ++t) {
    float4 a0 = ab[t * 4 + 0], a1 = ab[t * 4 + 1];
    float4 a2 = ab[t * 4 + 2], a3 = ab[t * 4 + 3];
    float av[S_] = {a0.x, a0.y, a0.z, a0.w, a1.x, a1.y, a1.z, a1.w,
                    a2.x, a2.y, a2.z, a2.w, a3.x, a3.y, a3.z, a3.w};
    float2 acc = make_float2(0.f, 0.f);
#pragma unroll
    for (int s = 0; s < S_; ++s) {
      acc.x += av[s] * ssf[s].x;
      acc.y += av[s] * ssf[s].y;
    }
    *(float2*)(ob + (size_t)t * D_) = acc;
  }
}

// ---------------------------------------------------------------------------
extern "C" void kernel_launch(void* const* d_in, const int* in_sizes, int n_in,
                              void* d_out, int out_size, void* d_ws, size_t ws_size,
                              hipStream_t stream) {
  const float* x          = (const float*)d_in[0];  // [B,T,D]
  const float* centers    = (const float*)d_in[1];  // [S,D]
  const float* log_scales = (const float*)d_in[2];  // [S]
  const float* Wv         = (const float*)d_in[3];  // [D,D]
  const float* Wo         = (const float*)d_in[4];  // [D,D]
  float* out = (float*)d_out;                       // [B,T,D]

  // workspace layout (floats): attn | ts | tmp | ss_o
  float* attn = (float*)d_ws;                        // B*T*S   = 2 MB
  float* ts   = attn + (size_t)B_ * T_ * S_;         // B*S*D   = 128 KB
  float* tmp  = ts + (size_t)B_ * S_ * D_;           // B*S*D   = 128 KB
  float* ss_o = tmp + (size_t)B_ * S_ * D_;          // B*S*D   = 128 KB

  // zero only the atomic target (tiny, L2-resident fill)
  hipMemsetAsync(ts, 0, (size_t)B_ * S_ * D_ * sizeof(float), stream);

  attn_ts_k<<<B_ * (T_ / CHUNK), 256, 0, stream>>>(x, centers, log_scales, attn, ts);
  proj_k<<<512, 256, 0, stream>>>(ts, Wv, tmp);    // tmp = ts @ Wv^T
  proj_k<<<512, 256, 0, stream>>>(tmp, Wo, ss_o);  // ss_o = tmp @ Wo^T
  out_k<<<B_ * (T_ / K4_TOK), 256, 0, stream>>>(attn, ss_o, out);
}

// Round 4
// 183.482 us; speedup vs baseline: 1.1316x; 1.1316x over previous
//
#include <hip/hip_runtime.h>
#include <math.h>

// Problem constants (from reference): B=4, T=8192, D=512, S=16
#define B_ 4
#define T_ 8192
#define D_ 512
#define S_ 16

// tokens per block for attn_ts_k / out_k (32 -> 1024 blocks).
#define CHUNK 32

// ---------------------------------------------------------------------------
// JOURNAL (measured, gfx950):
// R0: attn(64tok,c_reg,124regs)=57.7us, out(64tok,float2 ssf)~60, total 177.5
// R1: launch_bounds(...,4) w/ 128-reg need -> 64-reg cap SPILLS to scratch
//     (hbm 82->470MB, attn 141us, out 193us). NEVER cap below true need.
// R2: attn CHUNK=32 (1024 blocks, (256,2), 124 regs) = 50.4us PROVEN BEST.
//     out float4 ssf crossed 64-reg step -> occupancy halved, ~+25us. total 195.
// R3: attn lane-per-(token,splat): occupancy 36% BUT 16 lanes share each x
//     address -> 64B useful/load-instr (vs 1KB coalesced) -> VMEM-issue-bound,
//     80us. REGRESSION. Lesson: issue efficiency > occupancy.
// OCCUPANCY LAW: VGPR<=64 -> 4 waves/SIMD; 65..128 -> 2 waves/SIMD.
// R4: attn = exact R2. out_k: LDS-staged attn (kills wave-uniform 16B global
//     loads, the same disease as R3), 32 tok/block, float2 ssf, (256,4) cap
//     with true need ~55 regs.
// ---------------------------------------------------------------------------

__device__ __forceinline__ float dot4(float4 a, float4 b) {
  return a.x * b.x + a.y * b.y + a.z * b.z + a.w * b.w;
}

// ---------------------------------------------------------------------------
// Reduce-scatter across a wave: input vals[16] per lane (partial sums),
// output: full 64-lane sum of splat s=(lane>>2)&15, returned in every lane.
// ---------------------------------------------------------------------------
__device__ __forceinline__ float reduce_scatter16(float vals[S_], int lane) {
  {
    const int bit = (lane >> 5) & 1;
#pragma unroll
    for (int i = 0; i < 8; ++i) {
      float send = bit ? vals[i] : vals[i + 8];
      float keep = bit ? vals[i + 8] : vals[i];
      vals[i] = keep + __shfl_xor(send, 32, 64);
    }
  }
  {
    const int bit = (lane >> 4) & 1;
#pragma unroll
    for (int i = 0; i < 4; ++i) {
      float send = bit ? vals[i] : vals[i + 4];
      float keep = bit ? vals[i + 4] : vals[i];
      vals[i] = keep + __shfl_xor(send, 16, 64);
    }
  }
  {
    const int bit = (lane >> 3) & 1;
#pragma unroll
    for (int i = 0; i < 2; ++i) {
      float send = bit ? vals[i] : vals[i + 2];
      float keep = bit ? vals[i + 2] : vals[i];
      vals[i] = keep + __shfl_xor(send, 8, 64);
    }
  }
  {
    const int bit = (lane >> 2) & 1;
    float send = bit ? vals[0] : vals[1];
    float keep = bit ? vals[1] : vals[0];
    float v = keep + __shfl_xor(send, 4, 64);
    v += __shfl_xor(v, 2, 64);
    v += __shfl_xor(v, 1, 64);
    return v;
  }
}

// ---------------------------------------------------------------------------
// Fused attn + token->splat aggregation — EXACT R2 version (50.4 us proven).
// Block = 256 threads (4 waves); 1024 blocks = B * T/32 chunks.
// __launch_bounds__(256,2): allocator lands 124 VGPRs, no spill.
// ---------------------------------------------------------------------------
__global__ __launch_bounds__(256, 2) void attn_ts_k(const float* __restrict__ x,
                                                    const float* __restrict__ centers,
                                                    const float* __restrict__ log_scales,
                                                    float* __restrict__ attn,
                                                    float* __restrict__ ts) {
  __shared__ __align__(16) float a_s[CHUNK][S_];  // 2 KB
  const int lane = threadIdx.x & 63;
  const int w = threadIdx.x >> 6;  // 0..3
  const int myS = (lane >> 2) & 15;
  const int b = blockIdx.x >> 8;             // 256 chunks per batch
  const int t0 = (blockIdx.x & 255) * CHUNK; // 32 tokens per block

  // ---- Phase A ----
  {
    // centers in registers (128 VGPRs)
    float4 c_reg[S_][2];
#pragma unroll
    for (int s = 0; s < S_; ++s)
#pragma unroll
      for (int j = 0; j < 2; ++j)
        c_reg[s][j] = *(const float4*)(centers + s * D_ + (j << 8) + (lane << 2));

    float c2;
    {
      float vals[S_];
#pragma unroll
      for (int s = 0; s < S_; ++s)
        vals[s] = dot4(c_reg[s][0], c_reg[s][0]) + dot4(c_reg[s][1], c_reg[s][1]);
      c2 = reduce_scatter16(vals, lane);
    }
    const float sc = fminf(fmaxf(__expf(log_scales[myS]), 0.1f), 2.0f);
    const float inv2 = 0.5f / (sc * sc);

    const int tw = t0 + (w << 3);  // this wave's 8 tokens
    const float* xr = x + ((size_t)b * T_ + tw) * D_;
    float* ar = attn + ((size_t)b * T_ + tw) * S_;

    // prefetch first token pair
    float4 na0 = *(const float4*)(xr + (lane << 2));
    float4 na1 = *(const float4*)(xr + 256 + (lane << 2));
    float4 nb0 = *(const float4*)(xr + 512 + (lane << 2));
    float4 nb1 = *(const float4*)(xr + 768 + (lane << 2));

#pragma unroll 1
    for (int tt = 0; tt < 8; tt += 2) {
      float4 a0 = na0, a1 = na1, b0 = nb0, b1 = nb1;
      if (tt + 2 < 8) {  // prefetch next pair (uniform branch)
        const float* nx = xr + (size_t)(tt + 2) * D_;
        na0 = *(const float4*)(nx + (lane << 2));
        na1 = *(const float4*)(nx + 256 + (lane << 2));
        nb0 = *(const float4*)(nx + 512 + (lane << 2));
        nb1 = *(const float4*)(nx + 768 + (lane << 2));
      }

      float x2a = dot4(a0, a0) + dot4(a1, a1);
      float x2b = dot4(b0, b0) + dot4(b1, b1);

      float va[S_], vb[S_];
#pragma unroll
      for (int s = 0; s < S_; ++s) {
        va[s] = x2a - 2.f * (dot4(a0, c_reg[s][0]) + dot4(a1, c_reg[s][1]));
        vb[s] = x2b - 2.f * (dot4(b0, c_reg[s][0]) + dot4(b1, c_reg[s][1]));
      }

      float ra = reduce_scatter16(va, lane);
      float rb = reduce_scatter16(vb, lane);
      float la = -(ra + c2) * inv2;
      float lb = -(rb + c2) * inv2;

      float ma = la, mb = lb;
      ma = fmaxf(ma, __shfl_xor(ma, 4, 64));  mb = fmaxf(mb, __shfl_xor(mb, 4, 64));
      ma = fmaxf(ma, __shfl_xor(ma, 8, 64));  mb = fmaxf(mb, __shfl_xor(mb, 8, 64));
      ma = fmaxf(ma, __shfl_xor(ma, 16, 64)); mb = fmaxf(mb, __shfl_xor(mb, 16, 64));
      ma = fmaxf(ma, __shfl_xor(ma, 32, 64)); mb = fmaxf(mb, __shfl_xor(mb, 32, 64));
      float ea = __expf(la - ma), eb = __expf(lb - mb);
      float sa = ea, sb = eb;
      sa += __shfl_xor(sa, 4, 64);  sb += __shfl_xor(sb, 4, 64);
      sa += __shfl_xor(sa, 8, 64);  sb += __shfl_xor(sb, 8, 64);
      sa += __shfl_xor(sa, 16, 64); sb += __shfl_xor(sb, 16, 64);
      sa += __shfl_xor(sa, 32, 64); sb += __shfl_xor(sb, 32, 64);
      float aa = ea / sa, ab2 = eb / sb;

      if ((lane & 3) == 0) {
        ar[(size_t)tt * S_ + myS] = aa;
        ar[(size_t)(tt + 1) * S_ + myS] = ab2;
        a_s[(w << 3) + tt][myS] = aa;
        a_s[(w << 3) + tt + 1][myS] = ab2;
      }
    }
  }  // c_reg dies here

  __syncthreads();

  // ---- Phase B ----
  {
    const int d = threadIdx.x;  // owns cols d and d+256
    float2 acc[S_];
#pragma unroll
    for (int si = 0; si < S_; ++si) acc[si] = make_float2(0.f, 0.f);

    const float* xb = x + ((size_t)b * T_ + t0) * D_;

#pragma unroll 8
    for (int t = 0; t < CHUNK; ++t) {
      float xv0 = xb[(size_t)t * D_ + d];
      float xv1 = xb[(size_t)t * D_ + d + 256];
      const float4* ap = (const float4*)a_s[t];  // LDS broadcast
      float4 q0 = ap[0], q1 = ap[1], q2 = ap[2], q3 = ap[3];
      float av[S_] = {q0.x, q0.y, q0.z, q0.w, q1.x, q1.y, q1.z, q1.w,
                      q2.x, q2.y, q2.z, q2.w, q3.x, q3.y, q3.z, q3.w};
#pragma unroll
      for (int si = 0; si < S_; ++si) {
        acc[si].x += av[si] * xv0;
        acc[si].y += av[si] * xv1;
      }
    }

    float* tb = ts + (size_t)b * S_ * D_;
#pragma unroll
    for (int si = 0; si < S_; ++si) {
      atomicAdd(tb + si * D_ + d, acc[si].x);
      atomicAdd(tb + si * D_ + d + 256, acc[si].y);
    }
  }
}

// ---------------------------------------------------------------------------
// Kernel 2 (x2): out[r,e] = sum_k in[r,k] * W[e,k]   (r = 0..63 = b*S+s)
// Split-K=4 reduced in LDS (deterministic). 512 blocks x 256 threads.
// ---------------------------------------------------------------------------
__global__ __launch_bounds__(256) void proj_k(const float* __restrict__ in,
                                              const float* __restrict__ W,
                                              float* __restrict__ out) {
  __shared__ float red[4][64];
  const int r = blockIdx.x >> 3;
  const int eb = blockIdx.x & 7;
  const int el = threadIdx.x & 63;
  const int kc = threadIdx.x >> 6;
  const int e = (eb << 6) + el;

  const float4* w4 = (const float4*)(W + (size_t)e * D_ + kc * 128);
  const float4* i4 = (const float4*)(in + (size_t)r * D_ + kc * 128);
  float acc = 0.f;
#pragma unroll
  for (int k = 0; k < 32; ++k) acc += dot4(w4[k], i4[k]);

  red[kc][el] = acc;
  __syncthreads();
  if (kc == 0)
    out[(size_t)r * D_ + e] = red[0][el] + red[1][el] + red[2][el] + red[3][el];
}

// ---------------------------------------------------------------------------
// Kernel 3: out[b,t,e] = sum_s attn[b,t,s] * ss_o[b,s,e]
// R4 redesign: the R0/R2 versions loaded attn with wave-UNIFORM global
// float4 loads (all 64 lanes same address -> 16B useful/instr, 256 instrs
// per thread = VMEM-issue-bound; same disease as R3's phase A).
// Now: one coalesced float2 load per thread stages the chunk's attn (2 KB)
// into LDS; inner loop reads it as same-address LDS broadcasts.
// 32 tokens/block -> 1024 blocks (grid no longer caps residency at 2/CU).
// ssf stays float2[16] (32 regs); true need ~55 regs so the (256,4) cap
// (64 regs) does NOT spill (R1 lesson: only cap when need < cap).
// ---------------------------------------------------------------------------
__global__ __launch_bounds__(256, 4) void out_k(const float* __restrict__ attn,
                                                const float* __restrict__ ss_o,
                                                float* __restrict__ out) {
  __shared__ __align__(16) float a_s[CHUNK][S_];  // 2 KB
  const int chunks = T_ / CHUNK;  // 256
  const int b = blockIdx.x / chunks;
  const int t0 = (blockIdx.x % chunks) * CHUNK;
  const int w = threadIdx.x >> 6;
  const int lane = threadIdx.x & 63;
  const int e0 = (w << 7) + (lane << 1);  // 2 contiguous cols per thread

  // stage attn chunk: 32 tok x 16 splats = 512 floats = 256 float2 loads,
  // one per thread, fully coalesced (2 KB in one wave-wide burst per wave).
  ((float2*)a_s)[threadIdx.x] =
      ((const float2*)(attn + ((size_t)b * T_ + t0) * S_))[threadIdx.x];

  float2 ssf[S_];
  const float* sb = ss_o + (size_t)b * S_ * D_;
#pragma unroll
  for (int s = 0; s < S_; ++s) ssf[s] = *(const float2*)(sb + s * D_ + e0);

  __syncthreads();

  float* ob = out + ((size_t)b * T_ + t0) * D_ + e0;

#pragma unroll 4
  for (int t = 0; t < CHUNK; ++t) {
    const float4* ap = (const float4*)a_s[t];  // LDS broadcast (same addr)
    float4 q0 = ap[0], q1 = ap[1], q2 = ap[2], q3 = ap[3];
    float av[S_] = {q0.x, q0.y, q0.z, q0.w, q1.x, q1.y, q1.z, q1.w,
                    q2.x, q2.y, q2.z, q2.w, q3.x, q3.y, q3.z, q3.w};
    float2 acc = make_float2(0.f, 0.f);
#pragma unroll
    for (int s = 0; s < S_; ++s) {
      acc.x += av[s] * ssf[s].x;
      acc.y += av[s] * ssf[s].y;
    }
    *(float2*)(ob + (size_t)t * D_) = acc;
  }
}

// ---------------------------------------------------------------------------
extern "C" void kernel_launch(void* const* d_in, const int* in_sizes, int n_in,
                              void* d_out, int out_size, void* d_ws, size_t ws_size,
                              hipStream_t stream) {
  const float* x          = (const float*)d_in[0];  // [B,T,D]
  const float* centers    = (const float*)d_in[1];  // [S,D]
  const float* log_scales = (const float*)d_in[2];  // [S]
  const float* Wv         = (const float*)d_in[3];  // [D,D]
  const float* Wo         = (const float*)d_in[4];  // [D,D]
  float* out = (float*)d_out;                       // [B,T,D]

  // workspace layout (floats): attn | ts | tmp | ss_o
  float* attn = (float*)d_ws;                        // B*T*S   = 2 MB
  float* ts   = attn + (size_t)B_ * T_ * S_;         // B*S*D   = 128 KB
  float* tmp  = ts + (size_t)B_ * S_ * D_;           // B*S*D   = 128 KB
  float* ss_o = tmp + (size_t)B_ * S_ * D_;          // B*S*D   = 128 KB

  // zero only the atomic target (tiny, L2-resident fill)
  hipMemsetAsync(ts, 0, (size_t)B_ * S_ * D_ * sizeof(float), stream);

  attn_ts_k<<<B_ * (T_ / CHUNK), 256, 0, stream>>>(x, centers, log_scales, attn, ts);
  proj_k<<<512, 256, 0, stream>>>(ts, Wv, tmp);    // tmp = ts @ Wv^T
  proj_k<<<512, 256, 0, stream>>>(tmp, Wo, ss_o);  // ss_o = tmp @ Wo^T
  out_k<<<B_ * (T_ / CHUNK), 256, 0, stream>>>(attn, ss_o, out);
}

// Round 5
// 179.498 us; speedup vs baseline: 1.1567x; 1.0222x over previous
//
#include <hip/hip_runtime.h>
#include <hip/hip_bf16.h>
#include <math.h>

// Problem constants (from reference): B=4, T=8192, D=512, S=16
#define B_ 4
#define T_ 8192
#define D_ 512
#define S_ 16

// tokens per block for attn_ts_k (64 -> 512 blocks, 4 waves x 16 tokens)
#define CHUNK 64

// ---------------------------------------------------------------------------
// JOURNAL (measured, gfx950):
// R0: attn(64tok,c_reg VALU,124regs)=57.7us, out(64tok wave-uniform)=~50,
//     total 177.5 BEST SO FAR.
// R1: launch_bounds(...,4) w/ 128-reg need -> 64-reg cap SPILLS (hbm 82->470MB).
//     NEVER cap below true need.
// R2: attn CHUNK=32 = 50.4us. out float4 ssf crossed 64-reg step: total 195.
// R3: lane-per-(token,splat) phase A: 16 lanes share x addr -> 64B/instr,
//     VMEM-issue-bound, 80us. Issue efficiency > occupancy.
// R4: out_k LDS-staged + (256,4): rest got ~12us WORSE than R0 (cap-induced
//     pressure / extra barrier; wave-uniform loads of CACHED data were never
//     the bottleneck). attn back to 52us. total 183.5.
// R5: phase A -> MFMA (x*c^T on matrix pipe, 16 mfma vs ~1100 VALU FMA per
//     16 tokens; x^2/c^2 kept fp32-exact from fragment side-sums; only x*c
//     in bf16, logit RMS err ~1e-3). out_k = exact R0. OCCUPANCY LAW:
//     VGPR<=64 -> 4 w/SIMD; 65..128 -> 2 w/SIMD.
// ---------------------------------------------------------------------------

typedef __attribute__((ext_vector_type(8))) short bf16x8;   // 8 bf16 (4 VGPRs)
typedef __attribute__((ext_vector_type(4))) float f32x4;    // mfma C/D

__device__ __forceinline__ float dot4(float4 a, float4 b) {
  return a.x * b.x + a.y * b.y + a.z * b.z + a.w * b.w;
}

// pack 8 fp32 -> 8 bf16 (RNE via cvt_pk), as the short8 the mfma builtin takes
__device__ __forceinline__ bf16x8 pack8(float4 a, float4 b) {
  union { __hip_bfloat162 h[4]; bf16x8 v; } u;
  u.h[0] = __float22bfloat162_rn(make_float2(a.x, a.y));
  u.h[1] = __float22bfloat162_rn(make_float2(a.z, a.w));
  u.h[2] = __float22bfloat162_rn(make_float2(b.x, b.y));
  u.h[3] = __float22bfloat162_rn(make_float2(b.z, b.w));
  return u.v;
}

// ---------------------------------------------------------------------------
// Fused attn + token->splat aggregation. 512 blocks x 256 threads (4 waves).
//
// Phase A (MFMA): wave w owns tokens tw..tw+15. Per wave:
//   A = x[16 tok x 512], B = centers^T[512 x 16 splats], D = x.c^T via
//   16 x mfma_f32_16x16x32_bf16. Fragment layout (16x16x32):
//     A: lane l holds row m=l&15, k=(l>>4)*8+j  (8 bf16, one 32B global read)
//     B: lane l holds col n=l&15, k=(l>>4)*8+j  (centers row n)
//     D: lane l holds col n=l&15 (splat), rows (l>>4)*4+r (tokens) [m89-verified]
//   x2/c2 accumulated in fp32 from the SAME fragment loads (lane sums its
//   128-elem quarter; xor-16/32 completes). logit=(2xc - x2 - c2)*inv2.
//   Softmax across splats = xor-1/2/4/8 within 16-lane groups, 4 tokens/lane.
//
// Phase B: EXACT R0 (proven): thread owns cols d,d+256; streams chunk's x
// rows (L2-hot) against LDS-broadcast attn; 32 atomicAdds into ts.
// ---------------------------------------------------------------------------
__global__ __launch_bounds__(256, 2) void attn_ts_k(const float* __restrict__ x,
                                                    const float* __restrict__ centers,
                                                    const float* __restrict__ log_scales,
                                                    float* __restrict__ attn,
                                                    float* __restrict__ ts) {
  __shared__ __align__(16) float a_s[CHUNK][S_];  // 4 KB
  const int lane = threadIdx.x & 63;
  const int w = threadIdx.x >> 6;   // wave 0..3
  const int g = lane >> 4;          // k-group 0..3
  const int n = lane & 15;          // A-row token idx == B-col splat idx
  const int b = blockIdx.x >> 7;              // 128 chunks per batch
  const int t0 = (blockIdx.x & 127) * CHUNK;  // 64 tokens per block
  const int tw = t0 + (w << 4);               // this wave's 16 tokens

  // ---- Phase A ----
  {
    // B fragments: centers[n][g*8 + st*32 .. +7], c2 side-sum in fp32
    bf16x8 cf[16];
    float c2p = 0.f;
    const float* crow = centers + n * D_ + (g << 3);
#pragma unroll
    for (int st = 0; st < 16; ++st) {
      float4 c0 = *(const float4*)(crow + st * 32);
      float4 c1 = *(const float4*)(crow + st * 32 + 4);
      c2p += dot4(c0, c0) + dot4(c1, c1);
      cf[st] = pack8(c0, c1);
    }
    c2p += __shfl_xor(c2p, 16, 64);
    c2p += __shfl_xor(c2p, 32, 64);  // c2 for splat n (all lanes)

    const float sc = fminf(fmaxf(__expf(log_scales[n]), 0.1f), 2.0f);
    const float inv2 = 0.5f / (sc * sc);

    // K-loop: A fragments from x (token tw+n), x2 side-sum in fp32
    const float* xrow = x + ((size_t)b * T_ + tw + n) * D_ + (g << 3);
    f32x4 acc = {0.f, 0.f, 0.f, 0.f};
    float x2p = 0.f;
#pragma unroll
    for (int st = 0; st < 16; ++st) {
      float4 x0 = *(const float4*)(xrow + st * 32);
      float4 x1 = *(const float4*)(xrow + st * 32 + 4);
      x2p += dot4(x0, x0) + dot4(x1, x1);
      acc = __builtin_amdgcn_mfma_f32_16x16x32_bf16(pack8(x0, x1), cf[st], acc,
                                                    0, 0, 0);
    }
    x2p += __shfl_xor(x2p, 16, 64);
    x2p += __shfl_xor(x2p, 32, 64);  // x2 for token tw+n (all lanes)

    // logits: lane holds splat n, tokens (g*4+r)
    float lg[4];
#pragma unroll
    for (int r = 0; r < 4; ++r) {
      float x2r = __shfl(x2p, (lane & 48) | ((g << 2) + r), 64);
      lg[r] = (2.f * acc[r] - x2r - c2p) * inv2;
    }

    // softmax across splats (16-lane groups), 4 tokens per lane
    float mx[4] = {lg[0], lg[1], lg[2], lg[3]};
#pragma unroll
    for (int dlt = 1; dlt < 16; dlt <<= 1)
#pragma unroll
      for (int r = 0; r < 4; ++r) mx[r] = fmaxf(mx[r], __shfl_xor(mx[r], dlt, 64));
    float ev[4], sm[4];
#pragma unroll
    for (int r = 0; r < 4; ++r) { ev[r] = __expf(lg[r] - mx[r]); sm[r] = ev[r]; }
#pragma unroll
    for (int dlt = 1; dlt < 16; dlt <<= 1)
#pragma unroll
      for (int r = 0; r < 4; ++r) sm[r] += __shfl_xor(sm[r], dlt, 64);

    float* ar = attn + ((size_t)b * T_ + tw) * S_;
#pragma unroll
    for (int r = 0; r < 4; ++r) {
      float av = ev[r] / sm[r];
      int trow = (g << 2) + r;
      ar[trow * S_ + n] = av;             // 64B segments per 16-lane group
      a_s[(w << 4) + trow][n] = av;
    }
  }  // cf/acc die here

  __syncthreads();

  // ---- Phase B (exact R0, proven) ----
  {
    const int d = threadIdx.x;  // owns cols d and d+256
    float2 acc[S_];
#pragma unroll
    for (int si = 0; si < S_; ++si) acc[si] = make_float2(0.f, 0.f);

    const float* xb = x + ((size_t)b * T_ + t0) * D_;

#pragma unroll 8
    for (int t = 0; t < CHUNK; ++t) {
      float xv0 = xb[(size_t)t * D_ + d];
      float xv1 = xb[(size_t)t * D_ + d + 256];
      const float4* ap = (const float4*)a_s[t];  // LDS broadcast
      float4 q0 = ap[0], q1 = ap[1], q2 = ap[2], q3 = ap[3];
      float av[S_] = {q0.x, q0.y, q0.z, q0.w, q1.x, q1.y, q1.z, q1.w,
                      q2.x, q2.y, q2.z, q2.w, q3.x, q3.y, q3.z, q3.w};
#pragma unroll
      for (int si = 0; si < S_; ++si) {
        acc[si].x += av[si] * xv0;
        acc[si].y += av[si] * xv1;
      }
    }

    float* tb = ts + (size_t)b * S_ * D_;
#pragma unroll
    for (int si = 0; si < S_; ++si) {
      atomicAdd(tb + si * D_ + d, acc[si].x);
      atomicAdd(tb + si * D_ + d + 256, acc[si].y);
    }
  }
}

// ---------------------------------------------------------------------------
// Kernel 2 (x2): out[r,e] = sum_k in[r,k] * W[e,k]   (r = 0..63 = b*S+s)
// Split-K=4 reduced in LDS (deterministic). 512 blocks x 256 threads.
// ---------------------------------------------------------------------------
__global__ __launch_bounds__(256) void proj_k(const float* __restrict__ in,
                                              const float* __restrict__ W,
                                              float* __restrict__ out) {
  __shared__ float red[4][64];
  const int r = blockIdx.x >> 3;
  const int eb = blockIdx.x & 7;
  const int el = threadIdx.x & 63;
  const int kc = threadIdx.x >> 6;
  const int e = (eb << 6) + el;

  const float4* w4 = (const float4*)(W + (size_t)e * D_ + kc * 128);
  const float4* i4 = (const float4*)(in + (size_t)r * D_ + kc * 128);
  float acc = 0.f;
#pragma unroll
  for (int k = 0; k < 32; ++k) acc += dot4(w4[k], i4[k]);

  red[kc][el] = acc;
  __syncthreads();
  if (kc == 0)
    out[(size_t)r * D_ + e] = red[0][el] + red[1][el] + red[2][el] + red[3][el];
}

// ---------------------------------------------------------------------------
// Kernel 3: out[b,t,e] = sum_s attn[b,t,s] * ss_o[b,s,e]
// EXACT R0 form (512 blocks, 64 tokens, float2 ssf, wave-uniform attn loads
// hitting L1 — proven ~50us inside the 177.5 total; R2/R4 variants both
// regressed it).
// ---------------------------------------------------------------------------
#define K4_TOK 64
__global__ __launch_bounds__(256) void out_k(const float* __restrict__ attn,
                                             const float* __restrict__ ss_o,
                                             float* __restrict__ out) {
  const int chunks = T_ / K4_TOK;  // 128
  const int b = blockIdx.x / chunks;
  const int t0 = (blockIdx.x % chunks) * K4_TOK;
  const int w = threadIdx.x >> 6;
  const int lane = threadIdx.x & 63;
  const int e0 = (w << 7) + (lane << 1);

  float2 ssf[S_];
  const float* sb = ss_o + (size_t)b * S_ * D_;
#pragma unroll
  for (int s = 0; s < S_; ++s) ssf[s] = *(const float2*)(sb + s * D_ + e0);

  const float4* ab = (const float4*)(attn + ((size_t)b * T_ + t0) * S_);
  float* ob = out + ((size_t)b * T_ + t0) * D_ + e0;

#pragma unroll 4
  for (int t = 0; t < K4_TOK; ++t) {
    float4 a0 = ab[t * 4 + 0], a1 = ab[t * 4 + 1];
    float4 a2 = ab[t * 4 + 2], a3 = ab[t * 4 + 3];
    float av[S_] = {a0.x, a0.y, a0.z, a0.w, a1.x, a1.y, a1.z, a1.w,
                    a2.x, a2.y, a2.z, a2.w, a3.x, a3.y, a3.z, a3.w};
    float2 acc = make_float2(0.f, 0.f);
#pragma unroll
    for (int s = 0; s < S_; ++s) {
      acc.x += av[s] * ssf[s].x;
      acc.y += av[s] * ssf[s].y;
    }
    *(float2*)(ob + (size_t)t * D_) = acc;
  }
}

// ---------------------------------------------------------------------------
extern "C" void kernel_launch(void* const* d_in, const int* in_sizes, int n_in,
                              void* d_out, int out_size, void* d_ws, size_t ws_size,
                              hipStream_t stream) {
  const float* x          = (const float*)d_in[0];  // [B,T,D]
  const float* centers    = (const float*)d_in[1];  // [S,D]
  const float* log_scales = (const float*)d_in[2];  // [S]
  const float* Wv         = (const float*)d_in[3];  // [D,D]
  const float* Wo         = (const float*)d_in[4];  // [D,D]
  float* out = (float*)d_out;                       // [B,T,D]

  // workspace layout (floats): attn | ts | tmp | ss_o
  float* attn = (float*)d_ws;                        // B*T*S   = 2 MB
  float* ts   = attn + (size_t)B_ * T_ * S_;         // B*S*D   = 128 KB
  float* tmp  = ts + (size_t)B_ * S_ * D_;           // B*S*D   = 128 KB
  float* ss_o = tmp + (size_t)B_ * S_ * D_;          // B*S*D   = 128 KB

  // zero only the atomic target (tiny, L2-resident fill)
  hipMemsetAsync(ts, 0, (size_t)B_ * S_ * D_ * sizeof(float), stream);

  attn_ts_k<<<B_ * (T_ / CHUNK), 256, 0, stream>>>(x, centers, log_scales, attn, ts);
  proj_k<<<512, 256, 0, stream>>>(ts, Wv, tmp);    // tmp = ts @ Wv^T
  proj_k<<<512, 256, 0, stream>>>(tmp, Wo, ss_o);  // ss_o = tmp @ Wo^T
  out_k<<<B_ * (T_ / K4_TOK), 256, 0, stream>>>(attn, ss_o, out);
}